// Round 12
// baseline (137.736 us; speedup 1.0000x reference)
//
#include <hip/hip_runtime.h>
#include <math.h>

#define NP 8      // paths
#define ND 128    // D = c / P
#define NC 1024   // channels = NP*ND
#define NL 4096   // sequence length
#define NB 16     // batch
#define LN_EPS 1e-5f

#define NBLK 1024           // 4 blocks/CU x 256 CUs (co-resident)
#define NT   512
#define NCHUNK 16           // one chunk == one batch; 1 row per block per chunk
#define GRPS 32             // barrier groups (32 blocks each)

typedef float v4f __attribute__((ext_vector_type(4)));

__device__ __forceinline__ float hsum(v4f v) { return v.x + v.y + v.z + v.w; }
__device__ __forceinline__ float sigmoid_f(float z) { return 1.f / (1.f + expf(-z)); }

// expf-only tanh-GELU (no erff libcall). |err| ~1e-3 << 2.8e-2 threshold.
__device__ __forceinline__ float gelu_f(float s) {
    const float t = 0.7978845608028654f * (s + 0.044715f * s * s * s);
    const float e = expf(2.f * t);
    return 0.5f * s * (1.f + (e - 1.f) / (e + 1.f));
}

__device__ __forceinline__ float attn_pos(const float* __restrict__ sy, int pos,
                                          const float* __restrict__ c1w,
                                          const float* __restrict__ c2w,
                                          float w0, float w1, float cb) {
    const int p = pos >> 7, d = pos & 127;
    const float* rowp = sy + p * ND;
    float c1 = 0.f;
    #pragma unroll
    for (int t = 0; t < 5; ++t) {
        int dd = d + t - 2;
        float v = (dd >= 0 && dd < ND) ? rowp[dd] : 0.f;
        c1 += c1w[p * 5 + t] * v;
    }
    float c2 = 0.f;
    #pragma unroll
    for (int t = 0; t < 9; ++t) {
        int dd = d + t - 4;
        float v = (dd >= 0 && dd < ND) ? rowp[dd] : 0.f;
        c2 += c2w[p * 9 + t] * v;
    }
    return sigmoid_f(w0 * c1 + w1 * c2 + cb);
}

#define WREDUCE(ps) { ps += __shfl_down(ps, 32, 64); ps += __shfl_down(ps, 16, 64); \
    ps += __shfl_down(ps, 8, 64); ps += __shfl_down(ps, 4, 64); \
    ps += __shfl_down(ps, 2, 64); ps += __shfl_down(ps, 1, 64); }

// ========== Persistent pipelined fused kernel ==========
// iter c:  C(c-2): scale+store row staged 2 iters ago (own-thread LDS slots)
//          A(c):   load row c*1024+bid -> LDS buf[c&1], pool -> y, arrive(c)
//          wait(c-1) + B(c-1): redundant attn+gate for batch c-1 -> sscale
// The barrier wait hides under A's loads + C's store drain.
__global__ __launch_bounds__(NT, 4) void fused_kernel(
    const float* __restrict__ x, float* __restrict__ y,
    unsigned* __restrict__ garr, unsigned* __restrict__ grel,
    unsigned* __restrict__ root,
    const float* __restrict__ conv1_w, const float* __restrict__ conv2_w,
    const float* __restrict__ combine_w, const float* __restrict__ combine_b,
    const float* __restrict__ ln_g, const float* __restrict__ ln_b,
    const float* __restrict__ W1, const float* __restrict__ b1,
    const float* __restrict__ W2, const float* __restrict__ b2,
    float* __restrict__ out)
{
    const int tid  = threadIdx.x;
    const int bid  = blockIdx.x;
    const int grp  = bid >> 5;
    const bool lead = (bid & 31) == 0;
    const int pth  = bid >> 7;                 // path of this block's channel

    __shared__ v4f   srow[2][NL / 4];          // 32 KB double-buffered row
    __shared__ float sy[NC];                   // 4 KB pooled means of one batch
    __shared__ float sredP[8];
    __shared__ float sredA[8], sredB[8];
    __shared__ float scross[NP], sh[NP], sh2[2 * NP], sgate[NP], sml[2];
    __shared__ float sattn_own;
    __shared__ float sscale[2];

    for (int c = 0; c < NCHUNK + 2; ++c) {
        // ---- Phase C(c-2): scale + nt-store (same-thread LDS slots as A) ----
        if (c >= 2) {
            const int rowp = (c - 2) * NBLK + bid;
            const float sc = sscale[c & 1];
            v4f* orow = (v4f*)out + (size_t)rowp * (NL / 4);
            __builtin_nontemporal_store(srow[c & 1][tid]       * sc, &orow[tid]);
            __builtin_nontemporal_store(srow[c & 1][tid + 512] * sc, &orow[tid + 512]);
        }

        // ---- Phase A(c): HBM -> LDS + pool -> y, arrive ----
        if (c < NCHUNK) {
            const int rowc = c * NBLK + bid;
            const v4f* xr = (const v4f*)x + (size_t)rowc * (NL / 4);
            v4f v0 = xr[tid], v1 = xr[tid + 512];
            srow[c & 1][tid]       = v0;
            srow[c & 1][tid + 512] = v1;
            float ps = hsum(v0) + hsum(v1);
            WREDUCE(ps)
            if ((tid & 63) == 0) sredP[tid >> 6] = ps;
            __syncthreads();
            if (tid == 0) {
                float s = sredP[0] + sredP[1] + sredP[2] + sredP[3]
                        + sredP[4] + sredP[5] + sredP[6] + sredP[7];
                __hip_atomic_store(&y[rowc], s * (1.f / NL),
                                   __ATOMIC_RELAXED, __HIP_MEMORY_SCOPE_AGENT);
                // release orders the y store before the arrival count
                unsigned old = __hip_atomic_fetch_add(&garr[grp], 1u,
                                  __ATOMIC_RELEASE, __HIP_MEMORY_SCOPE_AGENT);
                if (old == (unsigned)(c * 32 + 31))
                    __hip_atomic_fetch_add(root, 1u,
                                  __ATOMIC_RELEASE, __HIP_MEMORY_SCOPE_AGENT);
            }
        }

        // ---- wait(c-1) + Phase B(c-1): gate for batch c-1 ----
        const int cb = c - 1;
        if (cb >= 0 && cb < NCHUNK) {
            if (tid == 0) {
                if (lead) {
                    while (__hip_atomic_load(root, __ATOMIC_ACQUIRE,
                                             __HIP_MEMORY_SCOPE_AGENT) < (unsigned)((cb + 1) * GRPS))
                        __builtin_amdgcn_s_sleep(2);
                    __hip_atomic_store(&grel[grp], (unsigned)(cb + 1),
                                       __ATOMIC_RELAXED, __HIP_MEMORY_SCOPE_AGENT);
                } else {
                    while (__hip_atomic_load(&grel[grp], __ATOMIC_RELAXED,
                                             __HIP_MEMORY_SCOPE_AGENT) < (unsigned)(cb + 1))
                        __builtin_amdgcn_s_sleep(2);
                }
            }
            __syncthreads();
            {   // stage y of batch cb (agent-scope: dodge stale XCD-L2 lines)
                const float* yb = y + cb * NC;
                sy[tid]       = __hip_atomic_load(&yb[tid],       __ATOMIC_RELAXED, __HIP_MEMORY_SCOPE_AGENT);
                sy[tid + 512] = __hip_atomic_load(&yb[tid + 512], __ATOMIC_RELAXED, __HIP_MEMORY_SCOPE_AGENT);
            }
            __syncthreads();
            const float w0 = combine_w[0], w1 = combine_w[1], cbb = combine_b[0];
            float a0 = attn_pos(sy, tid,       conv1_w, conv2_w, w0, w1, cbb);
            float a1 = attn_pos(sy, tid + 512, conv1_w, conv2_w, w0, w1, cbb);
            if (tid == (bid & 511)) sattn_own = (bid < 512) ? a0 : a1;
            float r0 = a0; WREDUCE(r0)
            if ((tid & 63) == 0) sredA[tid >> 6] = r0;
            float r1 = a1; WREDUCE(r1)
            if ((tid & 63) == 0) sredB[tid >> 6] = r1;
            __syncthreads();
            if (tid < NP) {
                float cr = (tid < 4) ? (sredA[2 * tid] + sredA[2 * tid + 1])
                                     : (sredB[2 * (tid - 4)] + sredB[2 * (tid - 4) + 1]);
                scross[tid] = cr * (1.f / ND);
            }
            __syncthreads();
            if (tid == 0) {
                float mu = 0.f;
                #pragma unroll
                for (int pp = 0; pp < NP; ++pp) mu += scross[pp];
                mu *= (1.f / NP);
                float var = 0.f;
                #pragma unroll
                for (int pp = 0; pp < NP; ++pp) { float dl = scross[pp] - mu; var += dl * dl; }
                sml[0] = mu;
                sml[1] = rsqrtf(var * (1.f / NP) + LN_EPS);
            }
            __syncthreads();
            if (tid < NP)
                sh[tid] = (scross[tid] - sml[0]) * sml[1] * ln_g[tid] + ln_b[tid];
            __syncthreads();
            if (tid < 2 * NP) {
                float s = b1[tid];
                #pragma unroll
                for (int pp = 0; pp < NP; ++pp) s += sh[pp] * W1[pp * (2 * NP) + tid];
                sh2[tid] = gelu_f(s);
            }
            __syncthreads();
            if (tid < NP) {
                float s = b2[tid];
                #pragma unroll
                for (int j = 0; j < 2 * NP; ++j) s += sh2[j] * W2[j * NP + tid];
                sgate[tid] = sigmoid_f(s);
            }
            __syncthreads();
            if (tid == 0) sscale[cb & 1] = sattn_own * sgate[pth];
            __syncthreads();          // sscale visible to next iteration's C
        }
    }
}

// ================= Fallback path (R4 kernels, 133 us) =================
__global__ __launch_bounds__(256) void pool_kernel(const float* __restrict__ x,
                                                   float* __restrict__ y) {
    const int wid  = threadIdx.x >> 6;
    const int lane = threadIdx.x & 63;
    const int row  = blockIdx.x * 4 + wid;
    const v4f* xr = (const v4f*)(x + (size_t)row * NL);
    float s = 0.f;
    #pragma unroll
    for (int i = 0; i < 16; ++i) {
        v4f v = xr[lane + i * 64];
        s += v.x + v.y + v.z + v.w;
    }
    #pragma unroll
    for (int off = 32; off; off >>= 1) s += __shfl_down(s, off, 64);
    if (lane == 0) y[row] = s * (1.f / NL);
}

__global__ __launch_bounds__(1024) void attn_kernel(
    const float* __restrict__ y,
    const float* __restrict__ conv1_w, const float* __restrict__ conv2_w,
    const float* __restrict__ combine_w, const float* __restrict__ combine_b,
    const float* __restrict__ ln_g, const float* __restrict__ ln_b,
    const float* __restrict__ W1, const float* __restrict__ b1,
    const float* __restrict__ W2, const float* __restrict__ b2,
    float* __restrict__ scale)
{
    const int b = blockIdx.x;
    const int tid = threadIdx.x;
    const int p = tid >> 7;
    const int d = tid & 127;

    __shared__ float sy[NC];
    __shared__ float sattn[NC];
    __shared__ float sred[16];
    __shared__ float scross[NP];
    __shared__ float sh[NP];
    __shared__ float sh2[2 * NP];
    __shared__ float sgate[NP];
    __shared__ float sml[2];

    sy[tid] = y[b * NC + tid];
    __syncthreads();

    const float* rowp = sy + p * ND;
    float c1 = 0.f;
    #pragma unroll
    for (int t = 0; t < 5; ++t) {
        int dd = d + t - 2;
        float v = (dd >= 0 && dd < ND) ? rowp[dd] : 0.f;
        c1 += conv1_w[p * 5 + t] * v;
    }
    float c2 = 0.f;
    #pragma unroll
    for (int t = 0; t < 9; ++t) {
        int dd = d + t - 4;
        float v = (dd >= 0 && dd < ND) ? rowp[dd] : 0.f;
        c2 += conv2_w[p * 9 + t] * v;
    }
    const float a = sigmoid_f(combine_w[0] * c1 + combine_w[1] * c2 + combine_b[0]);
    sattn[tid] = a;

    float rr = a;
    #pragma unroll
    for (int off = 32; off; off >>= 1) rr += __shfl_down(rr, off, 64);
    const int lane = tid & 63, wid = tid >> 6;
    if (lane == 0) sred[wid] = rr;
    __syncthreads();

    if (tid == 0) {
        float mu = 0.f, var = 0.f;
        #pragma unroll
        for (int pp = 0; pp < NP; ++pp) {
            scross[pp] = (sred[2 * pp] + sred[2 * pp + 1]) * (1.f / ND);
            mu += scross[pp];
        }
        mu *= (1.f / NP);
        #pragma unroll
        for (int pp = 0; pp < NP; ++pp) { float dl = scross[pp] - mu; var += dl * dl; }
        sml[0] = mu;
        sml[1] = rsqrtf(var * (1.f / NP) + LN_EPS);
    }
    __syncthreads();
    if (tid < NP)
        sh[tid] = (scross[tid] - sml[0]) * sml[1] * ln_g[tid] + ln_b[tid];
    __syncthreads();
    if (tid < 2 * NP) {
        float s = b1[tid];
        #pragma unroll
        for (int pp = 0; pp < NP; ++pp) s += sh[pp] * W1[pp * (2 * NP) + tid];
        sh2[tid] = gelu_f(s);
    }
    __syncthreads();
    if (tid < NP) {
        float s = b2[tid];
        #pragma unroll
        for (int j = 0; j < 2 * NP; ++j) s += sh2[j] * W2[j * NP + tid];
        sgate[tid] = sigmoid_f(s);
    }
    __syncthreads();

    scale[b * NC + tid] = sattn[tid] * sgate[p];
}

__global__ __launch_bounds__(256) void scale_kernel(const float* __restrict__ x,
                                                    const float* __restrict__ scale,
                                                    float* __restrict__ out) {
    const v4f* xv = (const v4f*)x;
    v4f* ov = (v4f*)out;
    const size_t n = (size_t)NB * NC * (NL / 4);
    const size_t stride = (size_t)gridDim.x * blockDim.x;
    for (size_t i = (size_t)blockIdx.x * blockDim.x + threadIdx.x; i < n; i += stride) {
        const float s = scale[i >> 10];
        v4f v = xv[i];
        v *= s;
        __builtin_nontemporal_store(v, &ov[i]);
    }
}

extern "C" void kernel_launch(void* const* d_in, const int* in_sizes, int n_in,
                              void* d_out, int out_size, void* d_ws, size_t ws_size,
                              hipStream_t stream) {
    const float* x         = (const float*)d_in[0];
    const float* conv1_w   = (const float*)d_in[1];
    const float* conv2_w   = (const float*)d_in[2];
    const float* combine_w = (const float*)d_in[3];
    const float* combine_b = (const float*)d_in[4];
    const float* ln_g      = (const float*)d_in[5];
    const float* ln_b      = (const float*)d_in[6];
    const float* W1        = (const float*)d_in[7];
    const float* b1        = (const float*)d_in[8];
    const float* W2        = (const float*)d_in[9];
    const float* b2        = (const float*)d_in[10];
    float* out = (float*)d_out;

    float* y        = (float*)d_ws;                    // [0,64KB): pooled means
    float* scale    = y + NB * NC;                     // [64KB,128KB): fallback only
    unsigned* garr  = (unsigned*)(void*)scale;         // coop: overlaps scale region
    unsigned* grel  = garr + GRPS;
    unsigned* root  = grel + GRPS;

    // zero barrier counters each launch (graph-capturable, deterministic)
    hipMemsetAsync((void*)garr, 0, (2 * GRPS + 16) * sizeof(unsigned), stream);

    int nb = 0;
    hipOccupancyMaxActiveBlocksPerMultiprocessor(&nb, fused_kernel, NT, 0);
    if (nb >= 4) {
        void* args[] = { (void*)&x, (void*)&y, (void*)&garr, (void*)&grel, (void*)&root,
                         (void*)&conv1_w, (void*)&conv2_w,
                         (void*)&combine_w, (void*)&combine_b,
                         (void*)&ln_g, (void*)&ln_b,
                         (void*)&W1, (void*)&b1, (void*)&W2, (void*)&b2,
                         (void*)&out };
        hipLaunchCooperativeKernel((const void*)fused_kernel, dim3(NBLK), dim3(NT),
                                   args, 0, stream);
    } else {
        pool_kernel<<<NB * NC / 4, 256, 0, stream>>>(x, y);
        attn_kernel<<<NB, 1024, 0, stream>>>(y, conv1_w, conv2_w, combine_w, combine_b,
                                             ln_g, ln_b, W1, b1, W2, b2, scale);
        scale_kernel<<<2048, 256, 0, stream>>>(x, scale, out);
    }
}